// Round 3
// baseline (307.081 us; speedup 1.0000x reference)
//
#include <hip/hip_runtime.h>

#define EPS 1e-8f
#define LN_EPS 1e-5f
#define NROWS 8192
#define SLEN 4096
#define PROBS_OFF 2097152   // 8192*256

typedef __attribute__((ext_vector_type(8))) short bf16x8;
typedef __attribute__((ext_vector_type(4))) float f32x4;

__device__ __forceinline__ short f2bf(float f) {
    unsigned u = __float_as_uint(f);
    unsigned r = (u + 0x7FFFu + ((u >> 16) & 1u)) >> 16;  // RNE
    return (short)r;
}

// ---------------- K1: one block per row, pure-global reads, full features ----------------
// No LDS staging: every read below is 16B-aligned in global memory; a row is
// 16 KB (L1-resident), thread windows overlap 3.5x which L1 absorbs. Thread t
// owns positions [8t, 8t+8); history [8t-20, 8t) comes from 5 guarded float4
// loads (zeros before row start reproduce the min(i+1,20) window count).
// Block computes S,Q,T across 8 waves and writes the FINAL 4 features to ws.
__global__ __launch_bounds__(512) void k_feat(const float* __restrict__ prices,
                                              float* __restrict__ ws) {
    __shared__ float red[8][3];
    __shared__ float tailv[2];   // [0]=p_m10 (pos 4086), [1]=p_last (pos 4095)

    const int t = threadIdx.x;
    const int b = blockIdx.x;
    const int lane = t & 63, wv = t >> 6;
    const float4* R4 = (const float4*)(prices + (size_t)b * SLEN);

    const float4 z4 = make_float4(0.f, 0.f, 0.f, 0.f);
    float4 s0 = R4[2 * t];
    float4 s1 = R4[2 * t + 1];
    float4 q0 = (2 * t - 5 >= 0) ? R4[2 * t - 5] : z4;
    float4 q1 = (2 * t - 4 >= 0) ? R4[2 * t - 4] : z4;
    float4 q2 = (2 * t - 3 >= 0) ? R4[2 * t - 3] : z4;
    float4 q3 = (2 * t - 2 >= 0) ? R4[2 * t - 2] : z4;
    float4 q4 = (2 * t - 1 >= 0) ? R4[2 * t - 1] : z4;

    // constant-index views (SROA-safe)
    float xv[8] = { s0.x, s0.y, s0.z, s0.w, s1.x, s1.y, s1.z, s1.w };
    float ov[8] = { q0.x, q0.y, q0.z, q0.w, q1.x, q1.y, q1.z, q1.w };

    // sum of the 19 values preceding p0 (zeros cover the row head)
    float W = q0.y + q0.z + q0.w
            + q1.x + q1.y + q1.z + q1.w
            + q2.x + q2.y + q2.z + q2.w
            + q3.x + q3.y + q3.z + q3.w
            + q4.x + q4.y + q4.z + q4.w;

    const float pf = (float)(8 * t);
    float sum = 0.0f, sq = 0.0f, ts = 0.0f;
    #pragma unroll
    for (int j = 0; j < 8; ++j) {
        float x = xv[j];
        W += (j == 0) ? x : (x - ov[j]);
        sum += x;
        sq = fmaf(x, x, sq);
        float c = fminf(pf + (float)(j + 1), 20.0f);
        // (x - W/c)/(W/c + EPS) == (x*c - W)/(W + EPS*c)   [c>0, W>=0.5]
        float num = fmaf(x, c, -W);
        float den = fmaf(EPS, c, W);
        ts += num * __builtin_amdgcn_rcpf(den);
    }

    if (t == 510) tailv[0] = xv[6];   // position 4086
    if (t == 511) tailv[1] = xv[7];   // position 4095

    #pragma unroll
    for (int off = 32; off > 0; off >>= 1) {
        sum += __shfl_xor(sum, off);
        sq  += __shfl_xor(sq,  off);
        ts  += __shfl_xor(ts,  off);
    }
    if (lane == 0) { red[wv][0] = sum; red[wv][1] = sq; red[wv][2] = ts; }
    __syncthreads();

    if (t == 0) {
        float S = 0.f, Q = 0.f, T = 0.f;
        #pragma unroll
        for (int w = 0; w < 8; ++w) { S += red[w][0]; Q += red[w][1]; T += red[w][2]; }
        float mean = S * (1.0f / 4096.0f);
        float var  = fmaxf((Q - 4096.0f * mean * mean) * (1.0f / 4095.0f), 0.0f);
        float p_m10 = tailv[0], p_last = tailv[1];
        float4 f;
        f.x = T * (1.0f / 4096.0f);
        f.y = (p_last - p_m10) / (p_m10 + EPS);
        f.z = (p_last - mean) / (mean + EPS);
        f.w = sqrtf(var) / (mean + EPS);
        ((float4*)ws)[b] = f;
    }
}

// ---------------- K2: encoder + LN + head (MFMA) + softmax ----------------
#define ROWS 16

__global__ __launch_bounds__(256) void k_head(
    const float* __restrict__ ws, float* __restrict__ out,
    const float* __restrict__ enc_w, const float* __restrict__ enc_b,
    const float* __restrict__ enc_g, const float* __restrict__ enc_bt,
    const float* __restrict__ w1, const float* __restrict__ b1,
    const float* __restrict__ w2, const float* __restrict__ b2)
{
    __shared__ float comb[ROWS][4];
    __shared__ short rfb[ROWS][264];   // bf16 rf tile, +8 pad
    __shared__ float hbuf[ROWS][68];   // padded

    const int t = threadIdx.x;
    const int r0 = blockIdx.x * ROWS;
    const int lane = t & 63, wave = t >> 6;
    const int l15 = lane & 15, q = lane >> 4;

    // features are final in ws now: straight copy to LDS
    if (t < ROWS) *(float4*)comb[t] = ((const float4*)ws)[r0 + t];

    // B-frags: wave w owns cols [16w,16w+16); B layout n=lane&15, k=q*8+j per k-tile
    bf16x8 bfrag[8];
    #pragma unroll
    for (int kt = 0; kt < 8; ++kt) {
        #pragma unroll
        for (int j = 0; j < 8; ++j) {
            int k = kt * 32 + q * 8 + j;
            bfrag[kt][j] = f2bf(w1[k * 64 + wave * 16 + l15]);
        }
    }

    const float ew0 = enc_w[wave * 256 + lane];
    const float ew1v = enc_w[wave * 256 + 64 + lane];
    const float ew2v = enc_w[wave * 256 + 128 + lane];
    const float ew3v = enc_w[wave * 256 + 192 + lane];
    const float ebv = enc_b[t], egv = enc_g[t], btv = enc_bt[t];

    __syncthreads();

    // encoder + relu + LayerNorm; 2 rows/iter for ILP on the shuffle chains
    for (int r = 0; r < ROWS; r += 2) {
        float4 cba = *(const float4*)comb[r];
        float4 cbb = *(const float4*)comb[r + 1];
        float va = fmaf(cba.x, ew0, fmaf(cba.y, ew1v, fmaf(cba.z, ew2v, fmaf(cba.w, ew3v, ebv))));
        float vb = fmaf(cbb.x, ew0, fmaf(cbb.y, ew1v, fmaf(cbb.z, ew2v, fmaf(cbb.w, ew3v, ebv))));
        va = fmaxf(va, 0.0f);
        vb = fmaxf(vb, 0.0f);
        float sma = va, smb = vb;
        #pragma unroll
        for (int off = 32; off > 0; off >>= 1) {
            sma += __shfl_xor(sma, off);
            smb += __shfl_xor(smb, off);
        }
        float mua = sma * (1.0f / 64.0f);
        float mub = smb * (1.0f / 64.0f);
        float da = va - mua, db = vb - mub;
        float vsa = da * da, vsb = db * db;
        #pragma unroll
        for (int off = 32; off > 0; off >>= 1) {
            vsa += __shfl_xor(vsa, off);
            vsb += __shfl_xor(vsb, off);
        }
        float ya = fmaf(da * rsqrtf(vsa * (1.0f / 64.0f) + LN_EPS), egv, btv);
        float yb = fmaf(db * rsqrtf(vsb * (1.0f / 64.0f) + LN_EPS), egv, btv);
        out[(size_t)(r0 + r) * 256 + t] = ya;       // regime_features fp32
        out[(size_t)(r0 + r + 1) * 256 + t] = yb;
        rfb[r][t] = f2bf(ya);
        rfb[r + 1][t] = f2bf(yb);
    }
    __syncthreads();

    // h = rf @ w1 via 16x16x32 bf16 MFMA; single m-tile (16 rows)
    f32x4 acc0 = {0.f, 0.f, 0.f, 0.f};
    #pragma unroll
    for (int kt = 0; kt < 8; ++kt) {
        bf16x8 a0 = *(const bf16x8*)&rfb[l15][kt * 32 + q * 8];
        acc0 = __builtin_amdgcn_mfma_f32_16x16x32_bf16(a0, bfrag[kt], acc0, 0, 0, 0);
    }

    const int col = wave * 16 + l15;
    const float b1v = b1[col];
    #pragma unroll
    for (int rg = 0; rg < 4; ++rg)
        hbuf[q * 4 + rg][col] = fmaxf(acc0[rg] + b1v, 0.0f);
    __syncthreads();

    // logits + softmax (quad per row); 4 independent fmaf chains for ILP
    if (t < 4 * ROWS) {
        int r = t >> 2, c = t & 3;
        float a0 = 0.f, a1 = 0.f, a2 = 0.f, a3 = 0.f;
        #pragma unroll
        for (int j = 0; j < 16; ++j) {
            a0 = fmaf(hbuf[r][j],      w2[j * 4 + c],        a0);
            a1 = fmaf(hbuf[r][16 + j], w2[(16 + j) * 4 + c], a1);
            a2 = fmaf(hbuf[r][32 + j], w2[(32 + j) * 4 + c], a2);
            a3 = fmaf(hbuf[r][48 + j], w2[(48 + j) * 4 + c], a3);
        }
        float lg = b2[c] + ((a0 + a1) + (a2 + a3));
        float mx = fmaxf(lg, __shfl_xor(lg, 1, 4));
        mx = fmaxf(mx, __shfl_xor(mx, 2, 4));
        float ex = __expf(lg - mx);
        float s2 = ex + __shfl_xor(ex, 1, 4);
        s2 += __shfl_xor(s2, 2, 4);
        out[PROBS_OFF + (size_t)(r0 + r) * 4 + c] = ex / s2;
    }
}

extern "C" void kernel_launch(void* const* d_in, const int* in_sizes, int n_in,
                              void* d_out, int out_size, void* d_ws, size_t ws_size,
                              hipStream_t stream) {
    const float* prices  = (const float*)d_in[0];
    const float* enc_w   = (const float*)d_in[1];
    const float* enc_b   = (const float*)d_in[2];
    const float* enc_g   = (const float*)d_in[3];
    const float* enc_bt  = (const float*)d_in[4];
    const float* head_w1 = (const float*)d_in[5];
    const float* head_b1 = (const float*)d_in[6];
    const float* head_w2 = (const float*)d_in[7];
    const float* head_b2 = (const float*)d_in[8];
    float* out = (float*)d_out;
    float* ws  = (float*)d_ws;    // 8192 rows x 4 final features

    k_feat<<<NROWS, 512, 0, stream>>>(prices, ws);
    k_head<<<NROWS / ROWS, 256, 0, stream>>>(ws, out, enc_w, enc_b, enc_g, enc_bt,
                                             head_w1, head_b1, head_w2, head_b2);
}

// Round 5
// 212.425 us; speedup vs baseline: 1.4456x; 1.4456x over previous
//
#include <hip/hip_runtime.h>

#define EPS 1e-8f
#define LN_EPS 1e-5f
#define NROWS 8192
#define SLEN 4096
#define PROBS_OFF 2097152   // 8192*256

typedef __attribute__((ext_vector_type(8))) short bf16x8;
typedef __attribute__((ext_vector_type(4))) float f32x4;

__device__ __forceinline__ short f2bf(float f) {
    unsigned u = __float_as_uint(f);
    unsigned r = (u + 0x7FFFu + ((u >> 16) & 1u)) >> 16;  // RNE
    return (short)r;
}

// pad 4 floats per 16: 4-aligned float4 slots stay contiguous and 16B-aligned
#define SLP(i) ((i) + ((((i) >> 4)) << 2))

// ---------------- K1: one block per whole row, coalesced LDS staging ----------------
// 256 threads stage the 4096-float row into LDS with 4 coalesced float4 loads
// each (lane-consecutive 1KB wave-loads — round 3 proved strided direct-global
// reads collapse to 465 GB/s on transaction count). Row is stored at +32
// floats; the 32-float head is zeroed so window reads are branch-free and
// reproduce the min(i+1,20) prefix behavior. Thread t owns elements
// [16t,16t+16), reads its 20-float history from LDS, computes rolling SMA20
// trend + sum/sumsq partials; thread 255 (holding p_last/p_m10 in registers)
// writes the FINAL 4 features to ws.
__global__ __launch_bounds__(256) void k_feat(const float* __restrict__ prices,
                                              float* __restrict__ ws) {
    __shared__ float sld[5156];   // SLP(4127)=5155; 20.6 KB
    __shared__ float red[4][3];

    const int t = threadIdx.x;
    const int b = blockIdx.x;
    const int lane = t & 63, wv = t >> 6;
    const float4* R4 = (const float4*)(prices + (size_t)b * SLEN);

    // stage: zeros for slots 0..7 (elements -32..-1), row at slots 8..1031
    if (t < 8) *(float4*)&sld[SLP(4 * t)] = make_float4(0.f, 0.f, 0.f, 0.f);
    {
        float4 g0 = R4[t];
        float4 g1 = R4[t + 256];
        float4 g2 = R4[t + 512];
        float4 g3 = R4[t + 768];
        *(float4*)&sld[SLP(4 * (t + 8))]   = g0;
        *(float4*)&sld[SLP(4 * (t + 264))] = g1;
        *(float4*)&sld[SLP(4 * (t + 520))] = g2;
        *(float4*)&sld[SLP(4 * (t + 776))] = g3;
    }
    __syncthreads();

    // element e lives at sld[SLP(e+32)]
    const int e0 = 16 * t + 32;
    float4 s0 = *(const float4*)&sld[SLP(e0)];
    float4 s1 = *(const float4*)&sld[SLP(e0 + 4)];
    float4 s2 = *(const float4*)&sld[SLP(e0 + 8)];
    float4 s3 = *(const float4*)&sld[SLP(e0 + 12)];
    float4 q0 = *(const float4*)&sld[SLP(e0 - 20)];
    float4 q1 = *(const float4*)&sld[SLP(e0 - 16)];
    float4 q2 = *(const float4*)&sld[SLP(e0 - 12)];
    float4 q3 = *(const float4*)&sld[SLP(e0 - 8)];
    float4 q4 = *(const float4*)&sld[SLP(e0 - 4)];

    // constant-index views (SROA-safe)
    float xv[16] = { s0.x, s0.y, s0.z, s0.w, s1.x, s1.y, s1.z, s1.w,
                     s2.x, s2.y, s2.z, s2.w, s3.x, s3.y, s3.z, s3.w };
    float ov[16] = { q0.x, q0.y, q0.z, q0.w, q1.x, q1.y, q1.z, q1.w,
                     q2.x, q2.y, q2.z, q2.w, q3.x, q3.y, q3.z, q3.w };

    // sum of the 19 values preceding element 16t (staged zeros cover the head)
    float W = q0.y + q0.z + q0.w
            + q1.x + q1.y + q1.z + q1.w
            + q2.x + q2.y + q2.z + q2.w
            + q3.x + q3.y + q3.z + q3.w
            + q4.x + q4.y + q4.z + q4.w;

    const float pf = (float)(16 * t);
    float sum = 0.0f, sq = 0.0f, ts = 0.0f;
    #pragma unroll
    for (int j = 0; j < 16; ++j) {
        float x = xv[j];
        W += (j == 0) ? x : (x - ov[j]);
        sum += x;
        sq = fmaf(x, x, sq);
        float c = fminf(pf + (float)(j + 1), 20.0f);
        // (x - W/c)/(W/c + EPS) == (x*c - W)/(W + EPS*c)   [c>0, W>=0.5]
        float num = fmaf(x, c, -W);
        float den = fmaf(EPS, c, W);
        ts += num * __builtin_amdgcn_rcpf(den);
    }

    #pragma unroll
    for (int off = 32; off > 0; off >>= 1) {
        sum += __shfl_xor(sum, off);
        sq  += __shfl_xor(sq,  off);
        ts  += __shfl_xor(ts,  off);
    }
    if (lane == 0) { red[wv][0] = sum; red[wv][1] = sq; red[wv][2] = ts; }
    __syncthreads();

    // thread 255 owns elements 4080..4095: p_m10 = el 4086 = s1.z, p_last = s3.w
    if (t == 255) {
        float S = red[0][0] + red[1][0] + red[2][0] + red[3][0];
        float Q = red[0][1] + red[1][1] + red[2][1] + red[3][1];
        float T = red[0][2] + red[1][2] + red[2][2] + red[3][2];
        float mean = S * (1.0f / 4096.0f);
        float var  = fmaxf((Q - 4096.0f * mean * mean) * (1.0f / 4095.0f), 0.0f);
        float p_m10 = s1.z, p_last = s3.w;
        float4 f;
        f.x = T * (1.0f / 4096.0f);
        f.y = (p_last - p_m10) / (p_m10 + EPS);
        f.z = (p_last - mean) / (mean + EPS);
        f.w = sqrtf(var) / (mean + EPS);
        ((float4*)ws)[b] = f;
    }
}

// ---------------- K2: encoder + LN + head (MFMA) + softmax ----------------
#define ROWS 16

__global__ __launch_bounds__(256) void k_head(
    const float* __restrict__ ws, float* __restrict__ out,
    const float* __restrict__ enc_w, const float* __restrict__ enc_b,
    const float* __restrict__ enc_g, const float* __restrict__ enc_bt,
    const float* __restrict__ w1, const float* __restrict__ b1,
    const float* __restrict__ w2, const float* __restrict__ b2)
{
    __shared__ float comb[ROWS][4];
    __shared__ short rfb[ROWS][264];   // bf16 rf tile, +8 pad
    __shared__ float hbuf[ROWS][68];   // padded

    const int t = threadIdx.x;
    const int r0 = blockIdx.x * ROWS;
    const int lane = t & 63, wave = t >> 6;
    const int l15 = lane & 15, q = lane >> 4;

    // features are final in ws: straight copy to LDS
    if (t < ROWS) *(float4*)comb[t] = ((const float4*)ws)[r0 + t];

    // B-frags: wave w owns cols [16w,16w+16); B layout n=lane&15, k=q*8+j per k-tile
    bf16x8 bfrag[8];
    #pragma unroll
    for (int kt = 0; kt < 8; ++kt) {
        #pragma unroll
        for (int j = 0; j < 8; ++j) {
            int k = kt * 32 + q * 8 + j;
            bfrag[kt][j] = f2bf(w1[k * 64 + wave * 16 + l15]);
        }
    }

    const float ew0 = enc_w[wave * 256 + lane];
    const float ew1v = enc_w[wave * 256 + 64 + lane];
    const float ew2v = enc_w[wave * 256 + 128 + lane];
    const float ew3v = enc_w[wave * 256 + 192 + lane];
    const float ebv = enc_b[t], egv = enc_g[t], btv = enc_bt[t];

    __syncthreads();

    // encoder + relu + LayerNorm; 2 rows/iter for ILP on the shuffle chains
    for (int r = 0; r < ROWS; r += 2) {
        float4 cba = *(const float4*)comb[r];
        float4 cbb = *(const float4*)comb[r + 1];
        float va = fmaf(cba.x, ew0, fmaf(cba.y, ew1v, fmaf(cba.z, ew2v, fmaf(cba.w, ew3v, ebv))));
        float vb = fmaf(cbb.x, ew0, fmaf(cbb.y, ew1v, fmaf(cbb.z, ew2v, fmaf(cbb.w, ew3v, ebv))));
        va = fmaxf(va, 0.0f);
        vb = fmaxf(vb, 0.0f);
        float sma = va, smb = vb;
        #pragma unroll
        for (int off = 32; off > 0; off >>= 1) {
            sma += __shfl_xor(sma, off);
            smb += __shfl_xor(smb, off);
        }
        float mua = sma * (1.0f / 64.0f);
        float mub = smb * (1.0f / 64.0f);
        float da = va - mua, db = vb - mub;
        float vsa = da * da, vsb = db * db;
        #pragma unroll
        for (int off = 32; off > 0; off >>= 1) {
            vsa += __shfl_xor(vsa, off);
            vsb += __shfl_xor(vsb, off);
        }
        float ya = fmaf(da * rsqrtf(vsa * (1.0f / 64.0f) + LN_EPS), egv, btv);
        float yb = fmaf(db * rsqrtf(vsb * (1.0f / 64.0f) + LN_EPS), egv, btv);
        out[(size_t)(r0 + r) * 256 + t] = ya;       // regime_features fp32
        out[(size_t)(r0 + r + 1) * 256 + t] = yb;
        rfb[r][t] = f2bf(ya);
        rfb[r + 1][t] = f2bf(yb);
    }
    __syncthreads();

    // h = rf @ w1 via 16x16x32 bf16 MFMA; single m-tile (16 rows)
    f32x4 acc0 = {0.f, 0.f, 0.f, 0.f};
    #pragma unroll
    for (int kt = 0; kt < 8; ++kt) {
        bf16x8 a0 = *(const bf16x8*)&rfb[l15][kt * 32 + q * 8];
        acc0 = __builtin_amdgcn_mfma_f32_16x16x32_bf16(a0, bfrag[kt], acc0, 0, 0, 0);
    }

    const int col = wave * 16 + l15;
    const float b1v = b1[col];
    #pragma unroll
    for (int rg = 0; rg < 4; ++rg)
        hbuf[q * 4 + rg][col] = fmaxf(acc0[rg] + b1v, 0.0f);
    __syncthreads();

    // logits + softmax (quad per row); 4 independent fmaf chains for ILP
    if (t < 4 * ROWS) {
        int r = t >> 2, c = t & 3;
        float a0 = 0.f, a1 = 0.f, a2 = 0.f, a3 = 0.f;
        #pragma unroll
        for (int j = 0; j < 16; ++j) {
            a0 = fmaf(hbuf[r][j],      w2[j * 4 + c],        a0);
            a1 = fmaf(hbuf[r][16 + j], w2[(16 + j) * 4 + c], a1);
            a2 = fmaf(hbuf[r][32 + j], w2[(32 + j) * 4 + c], a2);
            a3 = fmaf(hbuf[r][48 + j], w2[(48 + j) * 4 + c], a3);
        }
        float lg = b2[c] + ((a0 + a1) + (a2 + a3));
        float mx = fmaxf(lg, __shfl_xor(lg, 1, 4));
        mx = fmaxf(mx, __shfl_xor(mx, 2, 4));
        float ex = __expf(lg - mx);
        float s2 = ex + __shfl_xor(ex, 1, 4);
        s2 += __shfl_xor(s2, 2, 4);
        out[PROBS_OFF + (size_t)(r0 + r) * 4 + c] = ex / s2;
    }
}

extern "C" void kernel_launch(void* const* d_in, const int* in_sizes, int n_in,
                              void* d_out, int out_size, void* d_ws, size_t ws_size,
                              hipStream_t stream) {
    const float* prices  = (const float*)d_in[0];
    const float* enc_w   = (const float*)d_in[1];
    const float* enc_b   = (const float*)d_in[2];
    const float* enc_g   = (const float*)d_in[3];
    const float* enc_bt  = (const float*)d_in[4];
    const float* head_w1 = (const float*)d_in[5];
    const float* head_b1 = (const float*)d_in[6];
    const float* head_w2 = (const float*)d_in[7];
    const float* head_b2 = (const float*)d_in[8];
    float* out = (float*)d_out;
    float* ws  = (float*)d_ws;    // 8192 rows x 4 final features

    k_feat<<<NROWS, 256, 0, stream>>>(prices, ws);
    k_head<<<NROWS / ROWS, 256, 0, stream>>>(ws, out, enc_w, enc_b, enc_g, enc_bt,
                                             head_w1, head_b1, head_w2, head_b2);
}